// Round 1
// baseline (69.779 us; speedup 1.0000x reference)
//
#include <hip/hip_runtime.h>
#include <hip/hip_bf16.h>

// out[b,h,i,j] = sum_d q[b,i,h,d] * T[128 + x[b,j] - x[b,i], h*64+d]
// Round 6: remove the Tl LDS round-trip entirely. B-fragments are built
// directly from global et (fp32 -> bf16 in regs): the 8 bf16 elements of
// frag (nt, half) are exactly 2 contiguous float4 of row r = w*64+nt*16+c.
//  - 16 independent float4 et loads batched up front (16 KB in flight/wave
//    -> L2 latency hidden; was serialized load->cvt->ds_write per iter).
//  - one barrier instead of two; LDS = Ts only (18.5 KB, was 50.5 KB).
//  - gather phase: lane owns 4 consecutive j (float4 store, was 2x float2),
//    4x b32 LDS gather per row-pair, no divergent predicated reads.

#define S_LEN 512
#define NH 8
#define HD 64
#define EDIM 512
#define TI 16      // i-rows per block; grid = B*NH*(S/TI) = 512 -> 2 blocks/CU
#define NR 256
#define TIP 18     // Ts row pad (floats): 72B rows, 8B-aligned, bank spread

typedef __attribute__((ext_vector_type(8))) short bf16x8;
typedef __attribute__((ext_vector_type(4))) float f32x4;

__device__ __forceinline__ ushort2 pk_bf16(float a, float b) {
    union { __hip_bfloat162 h; ushort2 u; } v;
    v.h = __float22bfloat162_rn(float2{a, b});
    return v.u;
}

__device__ __forceinline__ bf16x8 pack8(float4 lo, float4 hi) {
    union { bf16x8 v; ushort2 u[4]; } r;
    r.u[0] = pk_bf16(lo.x, lo.y); r.u[1] = pk_bf16(lo.z, lo.w);
    r.u[2] = pk_bf16(hi.x, hi.y); r.u[3] = pk_bf16(hi.z, hi.w);
    return r.v;
}

__global__ __launch_bounds__(256) void relpos_kernel(
    const float* __restrict__ q,     // [B, S, H, D]
    const float* __restrict__ et,    // [257, E]
    const int*   __restrict__ x,     // [B, S]
    const int*   __restrict__ maxx_p,
    float*       __restrict__ out)   // [B, H, S, S]
{
    const int tid = threadIdx.x;
    const int per = S_LEN / TI;                  // 32
    const int b   = blockIdx.x / (NH * per);
    const int h   = (blockIdx.x / per) % NH;
    const int i0  = (blockIdx.x % per) * TI;

    __shared__ float Ts[NR][TIP];                // 18 KB scores, [r][i] layout
    __shared__ int   xi_s[TI];

    const int w    = tid >> 6;
    const int l    = tid & 63;
    const int quad = l >> 4;
    const int c    = l & 15;

    // --- A-fragment source: global fp32 q row (i0+c), issue first ---
    const float* qrow = q + (((size_t)b * S_LEN + i0 + c) * NH + h) * HD + quad * 8;
    const float4 qa0 = *(const float4*)(qrow);
    const float4 qa1 = *(const float4*)(qrow + 4);
    const float4 qb0 = *(const float4*)(qrow + 32);
    const float4 qb1 = *(const float4*)(qrow + 36);

    // --- B-fragment sources: 16 independent float4 from et, all in flight ---
    // frag (nt, half0) = T[r][quad*8 .. +7], (nt, half1) = T[r][32+quad*8 .. +7]
    float4 tb[16];
    #pragma unroll
    for (int nt = 0; nt < 4; ++nt) {
        const float* trow = et + (size_t)(w * 64 + nt * 16 + c) * EDIM + h * HD + quad * 8;
        tb[nt * 4 + 0] = *(const float4*)(trow);
        tb[nt * 4 + 1] = *(const float4*)(trow + 4);
        tb[nt * 4 + 2] = *(const float4*)(trow + 32);
        tb[nt * 4 + 3] = *(const float4*)(trow + 36);
    }

    if (tid < TI) xi_s[tid] = x[b * S_LEN + i0 + tid];
    const int4 xj4 = *(const int4*)(x + b * S_LEN + 4 * (tid & 127)); // lane's 4 j-cols
    const int maxx = maxx_p[0];

    // pack A while et loads are in flight (compiler waits vmcnt for q only)
    const bf16x8 a0 = pack8(qa0, qa1);
    const bf16x8 a1 = pack8(qb0, qb1);

    // --- MFMA: S[m][r] = sum_d Q[m][d] * T[r][d]; wave w covers r in w*64.. ---
    f32x4 acc[4];
    #pragma unroll
    for (int nt = 0; nt < 4; ++nt) {
        const bf16x8 b0 = pack8(tb[nt * 4 + 0], tb[nt * 4 + 1]);
        const bf16x8 b1 = pack8(tb[nt * 4 + 2], tb[nt * 4 + 3]);
        f32x4 a = (f32x4){0.f, 0.f, 0.f, 0.f};
        a = __builtin_amdgcn_mfma_f32_16x16x32_bf16(a0, b0, a, 0, 0, 0);
        a = __builtin_amdgcn_mfma_f32_16x16x32_bf16(a1, b1, a, 0, 0, 0);
        acc[nt] = a;
    }

    // C/D: lane l reg v holds D[m = quad*4 + v][n = c] -> Ts[r][m], 2x b64/nt
    #pragma unroll
    for (int nt = 0; nt < 4; ++nt) {
        const int r = w * 64 + nt * 16 + c;
        *(float2*)&Ts[r][quad * 4]     = float2{acc[nt][0], acc[nt][1]};
        *(float2*)&Ts[r][quad * 4 + 2] = float2{acc[nt][2], acc[nt][3]};
    }

    __syncthreads();

    // --- gather: lane owns rows {ii, ii+1}[tid>>7] x 4 j-cols, float4 stores ---
    float* obase = out + (((size_t)b * NH + h) * S_LEN + i0) * S_LEN;
    const int jg     = (tid & 127) * 4;
    const int rowsel = tid >> 7;
    #pragma unroll
    for (int ii = 0; ii < TI; ii += 2) {
        const int row = ii + rowsel;
        const int xi  = xi_s[row];
        float4 o;
        o.x = Ts[(maxx + xj4.x - xi) & 255][row];
        o.y = Ts[(maxx + xj4.y - xi) & 255][row];
        o.z = Ts[(maxx + xj4.z - xi) & 255][row];
        o.w = Ts[(maxx + xj4.w - xi) & 255][row];
        *(float4*)(obase + (size_t)row * S_LEN + jg) = o;
    }
}

extern "C" void kernel_launch(void* const* d_in, const int* in_sizes, int n_in,
                              void* d_out, int out_size, void* d_ws, size_t ws_size,
                              hipStream_t stream) {
    const float* q    = (const float*)d_in[0];
    const float* et   = (const float*)d_in[1];
    const int*   x    = (const int*)d_in[2];
    const int*   maxx = (const int*)d_in[3];
    float*       out  = (float*)d_out;

    const int B = in_sizes[2] / S_LEN;           // 2
    dim3 grid(B * NH * (S_LEN / TI));            // 512 blocks
    relpos_kernel<<<grid, 256, 0, stream>>>(q, et, x, maxx, out);
}